// Round 5
// baseline (28993.845 us; speedup 1.0000x reference)
//
#include <hip/hip_runtime.h>

typedef unsigned short u16;
typedef unsigned int u32;
typedef __bf16 bf16x8 __attribute__((ext_vector_type(8)));
typedef float f32x4 __attribute__((ext_vector_type(4)));
typedef u16 u16x8 __attribute__((ext_vector_type(8)));

#define AS1 __attribute__((address_space(1)))
#define AS3 __attribute__((address_space(3)))

constexpr int Bsz = 512;   // batch
constexpr int LATn = 128;  // latent
constexpr int Hn  = 1024;  // hidden
constexpr int G4H = 4096;  // 4*H
constexpr int NBLK = 256;

__device__ __forceinline__ u16 f2bf(float x){
  u32 u = __float_as_uint(x);
  return (u16)((u + 0x7FFFu + ((u >> 16) & 1u)) >> 16);
}
__device__ __forceinline__ float bf2f(u16 h){ return __uint_as_float(((u32)h) << 16); }

__device__ __forceinline__ float sigm(float x){
  float e = __builtin_amdgcn_exp2f(x * -1.44269504088896f);
  return __builtin_amdgcn_rcpf(1.0f + e);
}
__device__ __forceinline__ float tanh_f(float x){
  float e = __builtin_amdgcn_exp2f(x * -2.88539008177793f);
  return __builtin_amdgcn_rcpf(1.0f + e) * 2.0f - 1.0f;
}

__device__ __forceinline__ bf16x8 ld8(const u16* p){
  u16x8 v = *reinterpret_cast<const u16x8*>(p);
  return __builtin_bit_cast(bf16x8, v);
}

__device__ __forceinline__ void load16_lds(const u16* g, u16* l){
  __builtin_amdgcn_global_load_lds((AS1 void*)(u16*)g, (AS3 void*)l, 16, 0, 0);
}

// ---------------- repack: fp32 -> bf16 hi/lo, 8-j-tile gate-interleaved layout ----------------
// W_hh src row = g*1024 + jj ; packed drow = (jj>>3)*32 + g*8 + (jj&7)
__global__ void repack_kernel(
    const float* __restrict__ Whh, const float* __restrict__ b_ih, const float* __restrict__ b_hh,
    const float* __restrict__ Wih,
    u16* wp_hi, u16* wp_lo, float* bpack, float* wihpack, u32* cnt)
{
  const int idx0 = blockIdx.x * blockDim.x + threadIdx.x;
  const int stride = gridDim.x * blockDim.x;
  if (idx0 < 4) cnt[idx0] = 0u;   // group-barrier counters: zero every launch
  for (int i = idx0; i < G4H * Hn; i += stride){
    int row = i >> 10, k = i & 1023;
    int g = row >> 10, jj = row & 1023;
    int drow = (jj >> 3) * 32 + g * 8 + (jj & 7);
    float x = Whh[i];
    u16 hi = f2bf(x);
    wp_hi[drow * 1024 + k] = hi;
    wp_lo[drow * 1024 + k] = f2bf(x - bf2f(hi));
  }
  for (int i = idx0; i < G4H; i += stride){
    int g = i >> 10, jj = i & 1023;
    int drow = (jj >> 3) * 32 + g * 8 + (jj & 7);
    bpack[drow] = b_ih[i] + b_hh[i];
    wihpack[drow] = Wih[i];
  }
}

// ---------------- persistent LSTM kernel ----------------
// 256 blocks x 512 threads, plain launch, 1 block/CU (LDS-limited), grid == CU count.
// Block: rowg = (bid&7)>>2 (XCDs 0-3 -> rows 0-255, XCDs 4-7 -> rows 256-511),
//        jtile = ((bid>>3)<<2)|(bid&3)  (8 hidden units = 32 gate cols, both W-hi and W-lo in LDS).
// 8 waves = 4 bgroups (64 rows) x 2 k-halves. Per-XCD global set = 1.5 MB (fits 4 MB L2).
// Coherence: proven agent-fence + atomic-counter barrier, now 2 groups x 128 blocks.
__global__ __launch_bounds__(512, 1) void lstm_persist(
    const u16* __restrict__ wp_hi, const u16* __restrict__ wp_lo,
    const float* __restrict__ bpack, const float* __restrict__ wihpack,
    const float* __restrict__ Wout, const float* __restrict__ bout,
    const float* __restrict__ z,
    const float* __restrict__ Wzh, const float* __restrict__ Wzc,
    const float* __restrict__ bzh, const float* __restrict__ bzc,
    u16* hb_hi, u16* hb_lo,      // [2][512][1024] bf16 hi/lo, double-buffered
    float* ypart,                 // [2][512 rows][128 jtile]
    float* outp, const int* tlen, u32* cnt)
{
  __shared__ __align__(16) u16 ldsW[2 * 32768];  // 128 KiB: hi @0, lo @32768; [slab16][col32][slot8^swz][8]
  __shared__ float exch[4096];                   // 16 KiB k-half exchange (two phases)
  __shared__ float x_lds[256];

  const int tid = threadIdx.x;
  const int lane = tid & 63, w = tid >> 6;
  const int r = lane & 15, q = lane >> 4;
  const int kg = w & 1, bgroup = w >> 1;
  const int bid = blockIdx.x;
  const int rowg = (bid & 7) >> 2;
  const int jtile = ((bid >> 3) << 2) | (bid & 3);
  const int T = tlen[0];

  // ---- stage Whi + Wlo into LDS (once) ----
  {
    const int a = tid >> 8;                 // 0 = hi, 1 = lo (wave-uniform)
    const int rem = tid & 255;
    const int col = rem >> 3, sp = rem & 7;
    const u16* wp = (a ? wp_lo : wp_hi) + (size_t)(jtile * 32 + col) * 1024 + (sp ^ (col & 7)) * 8;
    u16* dst = &ldsW[a * 32768 + (w & 3) * 512];   // wave-uniform base; HW adds lane*16B
    #pragma unroll 4
    for (int slab = 0; slab < 16; ++slab)
      load16_lds(wp + slab * 64, dst + slab * 2048);
  }

  // per-lane constants
  float bias_r[2], wih_r[2];
  #pragma unroll
  for (int nt = 0; nt < 2; ++nt){
    bias_r[nt] = bpack[jtile * 32 + nt * 16 + r];
    wih_r[nt]  = wihpack[jtile * 32 + nt * 16 + r];
  }
  const int jglob = jtile * 8 + (r & 7);
  const float wout_r = Wout[jglob];
  const float bo = bout[0];

  // ---- init: h0/c0 in fp32 scalar (once) ----
  float creg[16];
  if (kg == 0){
    const float* wzhp = Wzh + jglob * LATn;
    const float* wzcp = Wzc + jglob * LATn;
    const float bh0 = bzh[jglob], bc0 = bzc[jglob];
    #pragma unroll
    for (int mt = 0; mt < 4; ++mt)
      #pragma unroll
      for (int e = 0; e < 4; ++e){
        const int row = rowg * 256 + bgroup * 64 + mt * 16 + q * 4 + e;
        const float* zr = z + row * LATn;
        float sh = bh0, sc = bc0;
        for (int k = 0; k < LATn; ++k){
          const float zv = zr[k];
          sh = fmaf(zv, wzhp[k], sh);
          sc = fmaf(zv, wzcp[k], sc);
        }
        const int idx = mt * 4 + e;
        creg[idx] = tanh_f(sc);
        const float h0 = tanh_f(sh);
        if (r < 8){
          const u16 hi = f2bf(h0);
          hb_hi[row * Hn + jglob] = hi;
          hb_lo[row * Hn + jglob] = f2bf(h0 - bf2f(hi));
        }
      }
  }
  if (tid < 256) x_lds[tid] = 0.0f;
  __syncthreads();

  // ---- group barrier (128 blocks sharing rowg); proven protocol, capped spin ----
  __builtin_amdgcn_fence(__ATOMIC_RELEASE, "agent");
  __syncthreads();
  if (tid == 0){
    __hip_atomic_fetch_add(cnt + rowg, 1u, __ATOMIC_RELAXED, __HIP_MEMORY_SCOPE_AGENT);
    for (int spin = 0; spin < (1 << 18); ++spin){
      if (__hip_atomic_load(cnt + rowg, __ATOMIC_RELAXED, __HIP_MEMORY_SCOPE_AGENT) >= 128u) break;
      __builtin_amdgcn_s_sleep(2);
    }
  }
  __syncthreads();
  __builtin_amdgcn_fence(__ATOMIC_ACQUIRE, "agent");

  // ---- time loop ----
  #pragma unroll 1
  for (int t = 0; t < T; ++t){
    const int pb = t & 1;
    const u16* hs_hi = hb_hi + pb * (Bsz * Hn);
    const u16* hs_lo = hb_lo + pb * (Bsz * Hn);
    u16* hd_hi = hb_hi + (pb ^ 1) * (Bsz * Hn);
    u16* hd_lo = hb_lo + (pb ^ 1) * (Bsz * Hn);

    f32x4 acc[4][2];
    if (kg == 0){
      #pragma unroll
      for (int mt = 0; mt < 4; ++mt)
        #pragma unroll
        for (int e = 0; e < 4; ++e){
          const float xv = x_lds[bgroup * 64 + mt * 16 + q * 4 + e];
          #pragma unroll
          for (int nt = 0; nt < 2; ++nt)
            acc[mt][nt][e] = bias_r[nt] + xv * wih_r[nt];
        }
    } else {
      #pragma unroll
      for (int mt = 0; mt < 4; ++mt)
        #pragma unroll
        for (int nt = 0; nt < 2; ++nt)
          acc[mt][nt] = f32x4{0.f, 0.f, 0.f, 0.f};
    }

    const u16* ha_hi = hs_hi + (rowg * 256 + bgroup * 64 + r) * Hn + kg * 512 + q * 8;
    const u16* ha_lo = hs_lo + (rowg * 256 + bgroup * 64 + r) * Hn + kg * 512 + q * 8;

    #pragma unroll 4
    for (int c = 0; c < 16; ++c){
      const int ko = c * 32;
      const int lo_ = (kg * 8 + (c >> 1)) * 2048;
      const int slot = ((((c & 1) * 4 + q) ^ (r & 7))) * 8;
      bf16x8 ahi[4], alo[4];
      #pragma unroll
      for (int mt = 0; mt < 4; ++mt){
        ahi[mt] = ld8(ha_hi + mt * 16 * Hn + ko);
        alo[mt] = ld8(ha_lo + mt * 16 * Hn + ko);
      }
      bf16x8 bhi[2], blo[2];
      #pragma unroll
      for (int nt = 0; nt < 2; ++nt){
        bhi[nt] = ld8(&ldsW[lo_ + (nt * 16 + r) * 64 + slot]);
        blo[nt] = ld8(&ldsW[32768 + lo_ + (nt * 16 + r) * 64 + slot]);
      }
      #pragma unroll
      for (int mt = 0; mt < 4; ++mt)
        #pragma unroll
        for (int nt = 0; nt < 2; ++nt){
          acc[mt][nt] = __builtin_amdgcn_mfma_f32_16x16x32_bf16(ahi[mt], bhi[nt], acc[mt][nt], 0, 0, 0);
          acc[mt][nt] = __builtin_amdgcn_mfma_f32_16x16x32_bf16(ahi[mt], blo[nt], acc[mt][nt], 0, 0, 0);
          acc[mt][nt] = __builtin_amdgcn_mfma_f32_16x16x32_bf16(alo[mt], bhi[nt], acc[mt][nt], 0, 0, 0);
        }
    }

    // ---- k-half exchange through LDS, two phases (mt 0,1 then 2,3) ----
    #pragma unroll
    for (int ph = 0; ph < 2; ++ph){
      __syncthreads();
      if (kg == 1){
        #pragma unroll
        for (int ml = 0; ml < 2; ++ml)
          #pragma unroll
          for (int nt = 0; nt < 2; ++nt)
            #pragma unroll
            for (int e = 0; e < 4; ++e)
              exch[(((bgroup * 2 + ml) * 2 + nt) * 4 + e) * 64 + lane] = acc[ph * 2 + ml][nt][e];
      }
      __syncthreads();
      if (kg == 0){
        #pragma unroll
        for (int ml = 0; ml < 2; ++ml)
          #pragma unroll
          for (int nt = 0; nt < 2; ++nt)
            #pragma unroll
            for (int e = 0; e < 4; ++e)
              acc[ph * 2 + ml][nt][e] += exch[(((bgroup * 2 + ml) * 2 + nt) * 4 + e) * 64 + lane];
      }
    }

    // ---- pointwise LSTM cell (kg0 waves; gates recombined via xor-8 shfl) ----
    if (kg == 0){
      float pp[16];
      #pragma unroll
      for (int mt = 0; mt < 4; ++mt)
        #pragma unroll
        for (int e = 0; e < 4; ++e){
          const int idx = mt * 4 + e;
          const float p0 = acc[mt][0][e], p1 = acc[mt][1][e];
          const float q0 = __shfl_xor(p0, 8, 64);
          const float q1 = __shfl_xor(p1, 8, 64);
          const bool hi8 = (r >> 3) != 0;
          const float vi = hi8 ? q0 : p0;
          const float vf = hi8 ? p0 : q0;
          const float vg = hi8 ? q1 : p1;
          const float vo = hi8 ? p1 : q1;
          const float gi = sigm(vi);
          const float gf = sigm(vf);
          const float gg = tanh_f(vg);
          const float go = sigm(vo);
          const float cn = gf * creg[idx] + gi * gg;
          creg[idx] = cn;
          const float hn = go * tanh_f(cn);
          if (r < 8){
            const int row = rowg * 256 + bgroup * 64 + mt * 16 + q * 4 + e;
            const u16 hi = f2bf(hn);
            hd_hi[row * Hn + jglob] = hi;
            hd_lo[row * Hn + jglob] = f2bf(hn - bf2f(hi));
          }
          pp[idx] = hn * wout_r;
        }
      #pragma unroll
      for (int m = 1; m < 8; m <<= 1)
        #pragma unroll
        for (int idx = 0; idx < 16; ++idx)
          pp[idx] += __shfl_xor(pp[idx], m, 64);
      if (r == 0){
        #pragma unroll
        for (int mt = 0; mt < 4; ++mt)
          #pragma unroll
          for (int e = 0; e < 4; ++e){
            const int row = rowg * 256 + bgroup * 64 + mt * 16 + q * 4 + e;
            ypart[pb * 65536 + row * 128 + jtile] = pp[mt * 4 + e];
          }
      }
    }

    // ---- group barrier ----
    __builtin_amdgcn_fence(__ATOMIC_RELEASE, "agent");
    __syncthreads();
    if (tid == 0){
      __hip_atomic_fetch_add(cnt + rowg, 1u, __ATOMIC_RELAXED, __HIP_MEMORY_SCOPE_AGENT);
      const u32 tgt = 128u * (u32)(t + 2);
      for (int spin = 0; spin < (1 << 18); ++spin){
        if (__hip_atomic_load(cnt + rowg, __ATOMIC_RELAXED, __HIP_MEMORY_SCOPE_AGENT) >= tgt) break;
        __builtin_amdgcn_s_sleep(2);
      }
    }
    __syncthreads();
    __builtin_amdgcn_fence(__ATOMIC_ACQUIRE, "agent");

    // ---- x phase: y[row] = b_out + sum over 128 jtiles (coalesced) ----
    {
      const int row_l = tid >> 1, half = tid & 1;
      const f32x4* yp4 = reinterpret_cast<const f32x4*>(
          ypart + pb * 65536 + (rowg * 256 + row_l) * 128 + half * 64);
      f32x4 sv = {0.f, 0.f, 0.f, 0.f};
      #pragma unroll
      for (int i = 0; i < 16; ++i) sv += yp4[i];
      float s = sv[0] + sv[1] + sv[2] + sv[3];
      s += __shfl_xor(s, 1, 64);
      if (half == 0){
        const float y = bo + s;
        x_lds[row_l] = y;
        if (jtile == 0) outp[(rowg * 256 + row_l) * T + t] = y;
      }
    }
    __syncthreads();
  }
}

extern "C" void kernel_launch(void* const* d_in, const int* in_sizes, int n_in,
                              void* d_out, int out_size, void* d_ws, size_t ws_size,
                              hipStream_t stream)
{
  const float* z    = (const float*)d_in[0];
  const float* Wzh  = (const float*)d_in[1];
  const float* bzh  = (const float*)d_in[2];
  const float* Wzc  = (const float*)d_in[3];
  const float* bzc  = (const float*)d_in[4];
  const float* Wih  = (const float*)d_in[5];
  const float* Whh  = (const float*)d_in[6];
  const float* b_ih = (const float*)d_in[7];
  const float* b_hh = (const float*)d_in[8];
  const float* Wout = (const float*)d_in[9];
  const float* bout = (const float*)d_in[10];
  const int*   tlen = (const int*)d_in[11];
  float* outp = (float*)d_out;

  char* ws = (char*)d_ws;
  size_t off = 0;
  auto alloc = [&](size_t bytes) -> char* {
    char* p = ws + off;
    off += (bytes + 255) & ~size_t(255);
    return p;
  };
  u16* wp_hi  = (u16*)alloc((size_t)G4H * Hn * 2);
  u16* wp_lo  = (u16*)alloc((size_t)G4H * Hn * 2);
  u16* hb_hi  = (u16*)alloc((size_t)2 * Bsz * Hn * 2);
  u16* hb_lo  = (u16*)alloc((size_t)2 * Bsz * Hn * 2);
  float* bpack   = (float*)alloc((size_t)G4H * 4);
  float* wihpack = (float*)alloc((size_t)G4H * 4);
  float* ypart   = (float*)alloc((size_t)2 * Bsz * 128 * 4);
  u32* cnt       = (u32*)alloc(256);

  repack_kernel<<<dim3(1024), dim3(256), 0, stream>>>(
      Whh, b_ih, b_hh, Wih, wp_hi, wp_lo, bpack, wihpack, cnt);

  lstm_persist<<<dim3(NBLK), dim3(512), 0, stream>>>(
      wp_hi, wp_lo, bpack, wihpack, Wout, bout,
      z, Wzh, Wzc, bzh, bzc, hb_hi, hb_lo, ypart, outp, tlen, cnt);
}

// Round 6
// 25009.175 us; speedup vs baseline: 1.1593x; 1.1593x over previous
//
#include <hip/hip_runtime.h>

typedef unsigned short u16;
typedef unsigned int u32;
typedef __bf16 bf16x8 __attribute__((ext_vector_type(8)));
typedef float f32x4 __attribute__((ext_vector_type(4)));
typedef u16 u16x8 __attribute__((ext_vector_type(8)));

#define AS1 __attribute__((address_space(1)))
#define AS3 __attribute__((address_space(3)))

constexpr int Bsz = 512;   // batch
constexpr int LATn = 128;  // latent
constexpr int Hn  = 1024;  // hidden
constexpr int G4H = 4096;  // 4*H
constexpr int NBLK = 256;

__device__ __forceinline__ u16 f2bf(float x){
  u32 u = __float_as_uint(x);
  return (u16)((u + 0x7FFFu + ((u >> 16) & 1u)) >> 16);
}
__device__ __forceinline__ float bf2f(u16 h){ return __uint_as_float(((u32)h) << 16); }

__device__ __forceinline__ float sigm(float x){
  float e = __builtin_amdgcn_exp2f(x * -1.44269504088896f);
  return __builtin_amdgcn_rcpf(1.0f + e);
}
__device__ __forceinline__ float tanh_f(float x){
  float e = __builtin_amdgcn_exp2f(x * -2.88539008177793f);
  return __builtin_amdgcn_rcpf(1.0f + e) * 2.0f - 1.0f;
}

__device__ __forceinline__ bf16x8 ld8(const u16* p){
  u16x8 v = *reinterpret_cast<const u16x8*>(p);
  return __builtin_bit_cast(bf16x8, v);
}

__device__ __forceinline__ void load16_lds(const u16* g, u16* l){
  __builtin_amdgcn_global_load_lds((AS1 void*)(u16*)g, (AS3 void*)l, 16, 0, 0);
}

// ---------------- repack: fold y-feedback into weights, fp32 -> bf16 hi/lo ----------------
// W'[k][gc] = Whh[gc][k] + Wout[k]*Wih[gc];  bias' = b_ih + b_hh + bo*Wih
// packed col (within 8-j tile): drow = (jj>>3)*32 + g*8 + (jj&7)
__global__ void repack_kernel(
    const float* __restrict__ Whh, const float* __restrict__ b_ih, const float* __restrict__ b_hh,
    const float* __restrict__ Wih, const float* __restrict__ Wout, const float* __restrict__ bout,
    u16* wp_hi, u16* wp_lo, float* bpack, float* wihpack, u32* cnt)
{
  const int idx0 = blockIdx.x * blockDim.x + threadIdx.x;
  const int stride = gridDim.x * blockDim.x;
  if (idx0 < 4) cnt[idx0] = 0u;   // group-barrier counters: zero every launch
  const float bo = bout[0];
  for (int i = idx0; i < G4H * Hn; i += stride){
    int row = i >> 10, k = i & 1023;
    int g = row >> 10, jj = row & 1023;
    int drow = (jj >> 3) * 32 + g * 8 + (jj & 7);
    float x = Whh[i] + Wout[k] * Wih[row];
    u16 hi = f2bf(x);
    wp_hi[drow * 1024 + k] = hi;
    wp_lo[drow * 1024 + k] = f2bf(x - bf2f(hi));
  }
  for (int i = idx0; i < G4H; i += stride){
    int g = i >> 10, jj = i & 1023;
    int drow = (jj >> 3) * 32 + g * 8 + (jj & 7);
    bpack[drow] = b_ih[i] + b_hh[i] + bo * Wih[i];
    wihpack[drow] = Wih[i];
  }
}

// ---------------- init: h0, c0, y_init (one block per batch row) ----------------
__global__ __launch_bounds__(256, 1) void init_kernel(
    const float* __restrict__ z,
    const float* __restrict__ Wzh, const float* __restrict__ bzh,
    const float* __restrict__ Wzc, const float* __restrict__ bzc,
    const float* __restrict__ Wout, const float* __restrict__ bout,
    u16* hb_hi, u16* hb_lo, float* c0buf, float* yinit)
{
  __shared__ float zrow[LATn];
  __shared__ float yred[256];
  const int b = blockIdx.x, tid = threadIdx.x;
  if (tid < LATn) zrow[tid] = z[b * LATn + tid];
  __syncthreads();
  float ysum = 0.f;
  #pragma unroll
  for (int jj = 0; jj < 4; ++jj){
    const int j = tid * 4 + jj;
    const float* wh = Wzh + (size_t)j * LATn;
    const float* wc = Wzc + (size_t)j * LATn;
    float sh = bzh[j], sc = bzc[j];
    for (int k = 0; k < LATn; ++k){
      const float zv = zrow[k];
      sh = fmaf(zv, wh[k], sh);
      sc = fmaf(zv, wc[k], sc);
    }
    const float h0 = tanh_f(sh);
    c0buf[(size_t)b * Hn + j] = tanh_f(sc);
    const u16 hi = f2bf(h0);
    hb_hi[(size_t)b * Hn + j] = hi;
    hb_lo[(size_t)b * Hn + j] = f2bf(h0 - bf2f(hi));
    ysum = fmaf(h0, Wout[j], ysum);
  }
  yred[tid] = ysum;
  __syncthreads();
  for (int s = 128; s > 0; s >>= 1){
    if (tid < s) yred[tid] += yred[tid + s];
    __syncthreads();
  }
  if (tid == 0) yinit[b] = yred[0] + bout[0];
}

// ---------------- persistent LSTM kernel ----------------
// 256 blocks x 512 threads, plain launch, 1 block/CU (LDS-limited), grid == CU count.
// rowg = (bid&7)>>2: XCDs 0-3 own rows 0-255, XCDs 4-7 rows 256-511.
// jtile = (bid&3)*32 + (bid>>3): each XCD owns 32 CONTIGUOUS jtiles -> 512B-contiguous h
// span per row per XCD (no cross-XCD false sharing on h / ypart writes).
// 8 waves = 8 bgroups x 32 rows, full K=1024 per wave (no exchange). W' hi+lo in LDS.
// y-feedback folded into W' -> single barrier per step; y-output reduced off-path.
__global__ __launch_bounds__(512, 1) void lstm_persist(
    const u16* __restrict__ wp_hi, const u16* __restrict__ wp_lo,
    const float* __restrict__ bpack, const float* __restrict__ wihpack,
    const float* __restrict__ Wout, const float* __restrict__ bout,
    const float* __restrict__ c0buf, const float* __restrict__ yinit,
    u16* hb_hi, u16* hb_lo,      // [2][512][1024] bf16 hi/lo, double-buffered
    float* ypart,                 // [2][512 rows][128 jtile]
    float* outp, const int* tlen, u32* cnt)
{
  __shared__ __align__(16) u16 ldsW[2 * 32768];  // 128 KiB: hi @0, lo @32768; [slab16][col32][slot8^swz][8]
  __shared__ float redbuf[8];

  const int tid = threadIdx.x;
  const int lane = tid & 63, w = tid >> 6;
  const int r = lane & 15, q = lane >> 4;
  const int bid = blockIdx.x;
  const int rowg = (bid & 7) >> 2;
  const int jtile = (bid & 3) * 32 + (bid >> 3);
  const int j = jtile * 8 + (r & 7);
  const int row0 = rowg * 256 + w * 32;
  const int T = tlen[0];

  // ---- stage W' hi + lo into LDS (once) ----
  {
    const int a = tid >> 8;                 // 0 = hi, 1 = lo (wave-uniform)
    const int rem = tid & 255;
    const int col = rem >> 3, sp = rem & 7;
    const u16* wp = (a ? wp_lo : wp_hi) + (size_t)(jtile * 32 + col) * 1024 + (sp ^ (col & 7)) * 8;
    u16* dst = &ldsW[a * 32768 + (w & 3) * 512];   // wave-uniform base; HW adds lane*16B
    #pragma unroll 4
    for (int slab = 0; slab < 16; ++slab)
      load16_lds(wp + slab * 64, dst + slab * 2048);
  }

  // per-lane constants
  float bias_r[2], wih_r[2];
  #pragma unroll
  for (int nt = 0; nt < 2; ++nt){
    bias_r[nt] = bpack[jtile * 32 + nt * 16 + r];
    wih_r[nt]  = wihpack[jtile * 32 + nt * 16 + r];
  }
  const float wout_r = Wout[j];
  const float bo = bout[0];

  // c0 into registers (computed by init_kernel; kernel-boundary coherence)
  float creg[8];
  #pragma unroll
  for (int mt = 0; mt < 2; ++mt)
    #pragma unroll
    for (int e = 0; e < 4; ++e)
      creg[mt * 4 + e] = c0buf[(size_t)(row0 + mt * 16 + q * 4 + e) * Hn + j];

  __syncthreads();   // W' staging complete (syncthreads drains vmcnt)

  // ---- time loop: one barrier per step ----
  #pragma unroll 1
  for (int t = 0; t < T; ++t){
    const int pb = t & 1;
    const u16* hs_hi = hb_hi + pb * (Bsz * Hn);
    const u16* hs_lo = hb_lo + pb * (Bsz * Hn);
    u16* hd_hi = hb_hi + (pb ^ 1) * (Bsz * Hn);
    u16* hd_lo = hb_lo + (pb ^ 1) * (Bsz * Hn);

    f32x4 acc[2][2];
    #pragma unroll
    for (int mt = 0; mt < 2; ++mt)
      #pragma unroll
      for (int nt = 0; nt < 2; ++nt)
        #pragma unroll
        for (int e = 0; e < 4; ++e)
          acc[mt][nt][e] = bias_r[nt];
    if (t == 0){
      // x0 = 0, not y_{-1}: subtract the folded y_init term once
      #pragma unroll
      for (int mt = 0; mt < 2; ++mt)
        #pragma unroll
        for (int e = 0; e < 4; ++e){
          const float yi = yinit[row0 + mt * 16 + q * 4 + e];
          #pragma unroll
          for (int nt = 0; nt < 2; ++nt)
            acc[mt][nt][e] -= yi * wih_r[nt];
        }
    }

    const u16* ha_hi = hs_hi + (size_t)(row0 + r) * Hn + q * 8;
    const u16* ha_lo = hs_lo + (size_t)(row0 + r) * Hn + q * 8;

    #pragma unroll 4
    for (int c = 0; c < 32; ++c){
      const int ko = c * 32;
      bf16x8 ahi[2], alo[2];
      #pragma unroll
      for (int mt = 0; mt < 2; ++mt){
        ahi[mt] = ld8(ha_hi + mt * 16 * Hn + ko);
        alo[mt] = ld8(ha_lo + mt * 16 * Hn + ko);
      }
      const int lo_ = (c >> 1) * 2048;
      const int slot = ((((c & 1) * 4 + q) ^ (r & 7))) * 8;
      bf16x8 bhi[2], blo[2];
      #pragma unroll
      for (int nt = 0; nt < 2; ++nt){
        bhi[nt] = ld8(&ldsW[lo_ + (nt * 16 + r) * 64 + slot]);
        blo[nt] = ld8(&ldsW[32768 + lo_ + (nt * 16 + r) * 64 + slot]);
      }
      #pragma unroll
      for (int mt = 0; mt < 2; ++mt)
        #pragma unroll
        for (int nt = 0; nt < 2; ++nt){
          acc[mt][nt] = __builtin_amdgcn_mfma_f32_16x16x32_bf16(ahi[mt], bhi[nt], acc[mt][nt], 0, 0, 0);
          acc[mt][nt] = __builtin_amdgcn_mfma_f32_16x16x32_bf16(ahi[mt], blo[nt], acc[mt][nt], 0, 0, 0);
          acc[mt][nt] = __builtin_amdgcn_mfma_f32_16x16x32_bf16(alo[mt], bhi[nt], acc[mt][nt], 0, 0, 0);
        }
    }

    // ---- pointwise LSTM cell (all waves; gates recombined via xor-8 shfl) ----
    float pp[8];
    #pragma unroll
    for (int mt = 0; mt < 2; ++mt)
      #pragma unroll
      for (int e = 0; e < 4; ++e){
        const int idx = mt * 4 + e;
        const float p0 = acc[mt][0][e], p1 = acc[mt][1][e];
        const float q0 = __shfl_xor(p0, 8, 64);
        const float q1 = __shfl_xor(p1, 8, 64);
        const bool hi8 = (r >> 3) != 0;
        const float vi = hi8 ? q0 : p0;
        const float vf = hi8 ? p0 : q0;
        const float vg = hi8 ? q1 : p1;
        const float vo = hi8 ? p1 : q1;
        const float gi = sigm(vi);
        const float gf = sigm(vf);
        const float gg = tanh_f(vg);
        const float go = sigm(vo);
        const float cn = gf * creg[idx] + gi * gg;
        creg[idx] = cn;
        const float hn = go * tanh_f(cn);
        if (r < 8){
          const int row = row0 + mt * 16 + q * 4 + e;
          const u16 hi = f2bf(hn);
          hd_hi[(size_t)row * Hn + j] = hi;
          hd_lo[(size_t)row * Hn + j] = f2bf(hn - bf2f(hi));
        }
        pp[idx] = hn * wout_r;
      }
    #pragma unroll
    for (int m = 1; m < 8; m <<= 1)
      #pragma unroll
      for (int idx = 0; idx < 8; ++idx)
        pp[idx] += __shfl_xor(pp[idx], m, 64);
    if (r == 0){
      #pragma unroll
      for (int mt = 0; mt < 2; ++mt)
        #pragma unroll
        for (int e = 0; e < 4; ++e)
          ypart[pb * 65536 + (row0 + mt * 16 + q * 4 + e) * 128 + jtile] = pp[mt * 4 + e];
    }

    // ---- group barrier (128 blocks sharing rowg); proven protocol, capped spin ----
    __builtin_amdgcn_fence(__ATOMIC_RELEASE, "agent");
    __syncthreads();
    if (tid == 0){
      __hip_atomic_fetch_add(cnt + rowg, 1u, __ATOMIC_RELAXED, __HIP_MEMORY_SCOPE_AGENT);
      const u32 tgt = 128u * (u32)(t + 1);
      for (int spin = 0; spin < (1 << 18); ++spin){
        if (__hip_atomic_load(cnt + rowg, __ATOMIC_RELAXED, __HIP_MEMORY_SCOPE_AGENT) >= tgt) break;
        __builtin_amdgcn_s_sleep(2);
      }
    }
    __syncthreads();
    __builtin_amdgcn_fence(__ATOMIC_ACQUIRE, "agent");

    // ---- y output: each block reduces its 2 rows (off critical path, 1 KB) ----
    {
      const int r0 = rowg * 256 + jtile * 2;
      if (tid < 256){
        const int rsel = tid >> 7, col = tid & 127;
        float v = ypart[pb * 65536 + (r0 + rsel) * 128 + col];
        #pragma unroll
        for (int m = 1; m < 64; m <<= 1) v += __shfl_xor(v, m, 64);
        if (lane == 0) redbuf[tid >> 6] = v;
      }
      __syncthreads();
      if (tid < 2) outp[(r0 + tid) * T + t] = redbuf[tid * 2] + redbuf[tid * 2 + 1] + bo;
    }
  }
}

extern "C" void kernel_launch(void* const* d_in, const int* in_sizes, int n_in,
                              void* d_out, int out_size, void* d_ws, size_t ws_size,
                              hipStream_t stream)
{
  const float* z    = (const float*)d_in[0];
  const float* Wzh  = (const float*)d_in[1];
  const float* bzh  = (const float*)d_in[2];
  const float* Wzc  = (const float*)d_in[3];
  const float* bzc  = (const float*)d_in[4];
  const float* Wih  = (const float*)d_in[5];
  const float* Whh  = (const float*)d_in[6];
  const float* b_ih = (const float*)d_in[7];
  const float* b_hh = (const float*)d_in[8];
  const float* Wout = (const float*)d_in[9];
  const float* bout = (const float*)d_in[10];
  const int*   tlen = (const int*)d_in[11];
  float* outp = (float*)d_out;

  char* ws = (char*)d_ws;
  size_t off = 0;
  auto alloc = [&](size_t bytes) -> char* {
    char* p = ws + off;
    off += (bytes + 255) & ~size_t(255);
    return p;
  };
  u16* wp_hi  = (u16*)alloc((size_t)G4H * Hn * 2);
  u16* wp_lo  = (u16*)alloc((size_t)G4H * Hn * 2);
  u16* hb_hi  = (u16*)alloc((size_t)2 * Bsz * Hn * 2);
  u16* hb_lo  = (u16*)alloc((size_t)2 * Bsz * Hn * 2);
  float* c0buf   = (float*)alloc((size_t)Bsz * Hn * 4);
  float* yinit   = (float*)alloc((size_t)Bsz * 4);
  float* bpack   = (float*)alloc((size_t)G4H * 4);
  float* wihpack = (float*)alloc((size_t)G4H * 4);
  float* ypart   = (float*)alloc((size_t)2 * Bsz * 128 * 4);
  u32* cnt       = (u32*)alloc(256);

  repack_kernel<<<dim3(1024), dim3(256), 0, stream>>>(
      Whh, b_ih, b_hh, Wih, Wout, bout, wp_hi, wp_lo, bpack, wihpack, cnt);

  init_kernel<<<dim3(Bsz), dim3(256), 0, stream>>>(
      z, Wzh, bzh, Wzc, bzc, Wout, bout, hb_hi, hb_lo, c0buf, yinit);

  lstm_persist<<<dim3(NBLK), dim3(512), 0, stream>>>(
      wp_hi, wp_lo, bpack, wihpack, Wout, bout, c0buf, yinit,
      hb_hi, hb_lo, ypart, outp, tlen, cnt);
}

// Round 8
// 10502.288 us; speedup vs baseline: 2.7607x; 2.3813x over previous
//
#include <hip/hip_runtime.h>

typedef unsigned short u16;
typedef unsigned int u32;
typedef __bf16 bf16x8 __attribute__((ext_vector_type(8)));
typedef float f32x4 __attribute__((ext_vector_type(4)));
typedef u16 u16x8 __attribute__((ext_vector_type(8)));

#define AS1 __attribute__((address_space(1)))
#define AS3 __attribute__((address_space(3)))

constexpr int Bsz = 512;   // batch
constexpr int LATn = 128;  // latent
constexpr int Hn  = 1024;  // hidden
constexpr int G4H = 4096;  // 4*H
constexpr int NBLK = 256;

__device__ __forceinline__ u16 f2bf(float x){
  u32 u = __float_as_uint(x);
  return (u16)((u + 0x7FFFu + ((u >> 16) & 1u)) >> 16);
}
__device__ __forceinline__ float bf2f(u16 h){ return __uint_as_float(((u32)h) << 16); }

__device__ __forceinline__ float sigm(float x){
  float e = __builtin_amdgcn_exp2f(x * -1.44269504088896f);
  return __builtin_amdgcn_rcpf(1.0f + e);
}
__device__ __forceinline__ float tanh_f(float x){
  float e = __builtin_amdgcn_exp2f(x * -2.88539008177793f);
  return __builtin_amdgcn_rcpf(1.0f + e) * 2.0f - 1.0f;
}

__device__ __forceinline__ bf16x8 ld8(const u16* p){
  u16x8 v = *reinterpret_cast<const u16x8*>(p);
  return __builtin_bit_cast(bf16x8, v);
}

__device__ __forceinline__ void load16_lds(const u16* g, u16* l){
  __builtin_amdgcn_global_load_lds((AS1 void*)(u16*)g, (AS3 void*)l, 16, 0, 0);
}

// ---------------- repack: fold y-feedback into weights, fp32 -> bf16 hi/lo ----------------
// W'[gc][k] = Whh[gc][k] + Wout[k]*Wih[gc];  bias' = b_ih + b_hh + bo*Wih
// packed col (within 8-j tile): drow = (jj>>3)*32 + g*8 + (jj&7)
__global__ void repack_kernel(
    const float* __restrict__ Whh, const float* __restrict__ b_ih, const float* __restrict__ b_hh,
    const float* __restrict__ Wih, const float* __restrict__ Wout, const float* __restrict__ bout,
    u16* wp_hi, u16* wp_lo, float* bpack, float* wihpack)
{
  const int idx0 = blockIdx.x * blockDim.x + threadIdx.x;
  const int stride = gridDim.x * blockDim.x;
  const float bo = bout[0];
  for (int i = idx0; i < G4H * Hn; i += stride){
    int row = i >> 10, k = i & 1023;
    int g = row >> 10, jj = row & 1023;
    int drow = (jj >> 3) * 32 + g * 8 + (jj & 7);
    float x = Whh[i] + Wout[k] * Wih[row];
    u16 hi = f2bf(x);
    wp_hi[drow * 1024 + k] = hi;
    wp_lo[drow * 1024 + k] = f2bf(x - bf2f(hi));
  }
  for (int i = idx0; i < G4H; i += stride){
    int g = i >> 10, jj = i & 1023;
    int drow = (jj >> 3) * 32 + g * 8 + (jj & 7);
    bpack[drow] = b_ih[i] + b_hh[i] + bo * Wih[i];
    wihpack[drow] = Wih[i];
  }
}

// ---------------- init: h0, c0, y_init (one block per batch row) ----------------
__global__ __launch_bounds__(256, 1) void init_kernel(
    const float* __restrict__ z,
    const float* __restrict__ Wzh, const float* __restrict__ bzh,
    const float* __restrict__ Wzc, const float* __restrict__ bzc,
    const float* __restrict__ Wout, const float* __restrict__ bout,
    u16* hb_hi, u16* hb_lo, float* cbuf, float* yinit)
{
  __shared__ float zrow[LATn];
  __shared__ float yred[256];
  const int b = blockIdx.x, tid = threadIdx.x;
  if (tid < LATn) zrow[tid] = z[b * LATn + tid];
  __syncthreads();
  float ysum = 0.f;
  #pragma unroll
  for (int jj = 0; jj < 4; ++jj){
    const int j = tid * 4 + jj;
    const float* wh = Wzh + (size_t)j * LATn;
    const float* wc = Wzc + (size_t)j * LATn;
    float sh = bzh[j], sc = bzc[j];
    for (int k = 0; k < LATn; ++k){
      const float zv = zrow[k];
      sh = fmaf(zv, wh[k], sh);
      sc = fmaf(zv, wc[k], sc);
    }
    const float h0 = tanh_f(sh);
    cbuf[(size_t)b * Hn + j] = tanh_f(sc);
    const u16 hi = f2bf(h0);
    hb_hi[(size_t)b * Hn + j] = hi;
    hb_lo[(size_t)b * Hn + j] = f2bf(h0 - bf2f(hi));
    ysum = fmaf(h0, Wout[j], ysum);
  }
  yred[tid] = ysum;
  __syncthreads();
  for (int s = 128; s > 0; s >>= 1){
    if (tid < s) yred[tid] += yred[tid + s];
    __syncthreads();
  }
  if (tid == 0) yinit[b] = yred[0] + bout[0];
}

// ---------------- per-step kernel (launched T times) ----------------
// 256 blocks x 512 threads, 1 block/CU (LDS-limited).
// rowg = (bid&7)>>2, jtile = (bid&3)*32 + (bid>>3); 8 waves x 32 rows; 8 j per block.
// W' hi+lo staged to LDS each step (L2/L3-resident); h double-buffered in global;
// c in global cbuf (disjoint RMW per block); y via device-scope atomicAdd.
// Kernel-boundary coherence: NO fences, NO barriers, NO spins.
__global__ __launch_bounds__(512, 1) void step_kernel(
    const u16* __restrict__ wp_hi, const u16* __restrict__ wp_lo,
    const float* __restrict__ bpack, const float* __restrict__ wihpack,
    const float* __restrict__ Wout, const float* __restrict__ bout,
    const float* __restrict__ yinit,
    u16* __restrict__ hb_hi, u16* __restrict__ hb_lo,
    float* __restrict__ cbuf,
    float* __restrict__ outp, const int* __restrict__ tlen, int t)
{
  __shared__ __align__(16) u16 ldsW[2 * 32768];  // 128 KiB: hi @0, lo @32768

  const int T = tlen[0];
  if (t >= T) return;

  const int tid = threadIdx.x;
  const int lane = tid & 63, w = tid >> 6;
  const int r = lane & 15, q = lane >> 4;
  const int bid = blockIdx.x;
  const int rowg = (bid & 7) >> 2;
  const int jtile = (bid & 3) * 32 + (bid >> 3);
  const int j = jtile * 8 + (r & 7);
  const int row0 = rowg * 256 + w * 32;

  // ---- stage W' hi + lo into LDS ----
  {
    const int a = tid >> 8;                 // 0 = hi, 1 = lo (wave-uniform)
    const int rem = tid & 255;
    const int col = rem >> 3, sp = rem & 7;
    const u16* wp = (a ? wp_lo : wp_hi) + (size_t)(jtile * 32 + col) * 1024 + (sp ^ (col & 7)) * 8;
    u16* dst = &ldsW[a * 32768 + (w & 3) * 512];   // wave-uniform base; HW adds lane*16B
    #pragma unroll 4
    for (int slab = 0; slab < 16; ++slab)
      load16_lds(wp + slab * 64, dst + slab * 2048);
  }

  // per-lane constants
  float bias_r[2], wih_r[2];
  #pragma unroll
  for (int nt = 0; nt < 2; ++nt){
    bias_r[nt] = bpack[jtile * 32 + nt * 16 + r];
    wih_r[nt]  = wihpack[jtile * 32 + nt * 16 + r];
  }
  const float wout_r = Wout[j];
  const float bo = bout[0];

  const int pb = t & 1;
  const u16* hs_hi = hb_hi + pb * (Bsz * Hn);
  const u16* hs_lo = hb_lo + pb * (Bsz * Hn);
  u16* hd_hi = hb_hi + (pb ^ 1) * (Bsz * Hn);
  u16* hd_lo = hb_lo + (pb ^ 1) * (Bsz * Hn);

  // c state for this thread's (row, j) set
  float creg[8];
  #pragma unroll
  for (int mt = 0; mt < 2; ++mt)
    #pragma unroll
    for (int e = 0; e < 4; ++e)
      creg[mt * 4 + e] = cbuf[(size_t)(row0 + mt * 16 + q * 4 + e) * Hn + j];

  f32x4 acc[2][2];
  #pragma unroll
  for (int mt = 0; mt < 2; ++mt)
    #pragma unroll
    for (int nt = 0; nt < 2; ++nt)
      #pragma unroll
      for (int e = 0; e < 4; ++e)
        acc[mt][nt][e] = bias_r[nt];
  if (t == 0){
    // x0 = 0, not y_{-1}: subtract the folded y_init term once
    #pragma unroll
    for (int mt = 0; mt < 2; ++mt)
      #pragma unroll
      for (int e = 0; e < 4; ++e){
        const float yi = yinit[row0 + mt * 16 + q * 4 + e];
        #pragma unroll
        for (int nt = 0; nt < 2; ++nt)
          acc[mt][nt][e] -= yi * wih_r[nt];
      }
  }

  __syncthreads();   // staging complete (barrier drains vmcnt)

  const u16* ha_hi = hs_hi + (size_t)(row0 + r) * Hn + q * 8;
  const u16* ha_lo = hs_lo + (size_t)(row0 + r) * Hn + q * 8;

  #pragma unroll 4
  for (int c = 0; c < 32; ++c){
    const int ko = c * 32;
    bf16x8 ahi[2], alo[2];
    #pragma unroll
    for (int mt = 0; mt < 2; ++mt){
      ahi[mt] = ld8(ha_hi + mt * 16 * Hn + ko);
      alo[mt] = ld8(ha_lo + mt * 16 * Hn + ko);
    }
    const int lo_ = (c >> 1) * 2048;
    const int slot = ((((c & 1) * 4 + q) ^ (r & 7))) * 8;
    bf16x8 bhi[2], blo[2];
    #pragma unroll
    for (int nt = 0; nt < 2; ++nt){
      bhi[nt] = ld8(&ldsW[lo_ + (nt * 16 + r) * 64 + slot]);
      blo[nt] = ld8(&ldsW[32768 + lo_ + (nt * 16 + r) * 64 + slot]);
    }
    #pragma unroll
    for (int mt = 0; mt < 2; ++mt)
      #pragma unroll
      for (int nt = 0; nt < 2; ++nt){
        acc[mt][nt] = __builtin_amdgcn_mfma_f32_16x16x32_bf16(ahi[mt], bhi[nt], acc[mt][nt], 0, 0, 0);
        acc[mt][nt] = __builtin_amdgcn_mfma_f32_16x16x32_bf16(ahi[mt], blo[nt], acc[mt][nt], 0, 0, 0);
        acc[mt][nt] = __builtin_amdgcn_mfma_f32_16x16x32_bf16(alo[mt], bhi[nt], acc[mt][nt], 0, 0, 0);
      }
  }

  // ---- pointwise LSTM cell (gates recombined via xor-8 shfl) ----
  float pp[8];
  #pragma unroll
  for (int mt = 0; mt < 2; ++mt)
    #pragma unroll
    for (int e = 0; e < 4; ++e){
      const int idx = mt * 4 + e;
      const float p0 = acc[mt][0][e], p1 = acc[mt][1][e];
      const float q0 = __shfl_xor(p0, 8, 64);
      const float q1 = __shfl_xor(p1, 8, 64);
      const bool hi8 = (r >> 3) != 0;
      const float vi = hi8 ? q0 : p0;
      const float vf = hi8 ? p0 : q0;
      const float vg = hi8 ? q1 : p1;
      const float vo = hi8 ? p1 : q1;
      const float gi = sigm(vi);
      const float gf = sigm(vf);
      const float gg = tanh_f(vg);
      const float go = sigm(vo);
      const float cn = gf * creg[idx] + gi * gg;
      creg[idx] = cn;
      const float hn = go * tanh_f(cn);
      const int row = row0 + mt * 16 + q * 4 + e;
      if (r < 8){
        const u16 hi = f2bf(hn);
        hd_hi[(size_t)row * Hn + j] = hi;
        hd_lo[(size_t)row * Hn + j] = f2bf(hn - bf2f(hi));
        cbuf[(size_t)row * Hn + j] = cn;
      }
      pp[idx] = hn * wout_r;
    }
  #pragma unroll
  for (int m = 1; m < 8; m <<= 1)
    #pragma unroll
    for (int idx = 0; idx < 8; ++idx)
      pp[idx] += __shfl_xor(pp[idx], m, 64);
  if (r == 0){
    #pragma unroll
    for (int mt = 0; mt < 2; ++mt)
      #pragma unroll
      for (int e = 0; e < 4; ++e){
        const int row = row0 + mt * 16 + q * 4 + e;
        const float v = pp[mt * 4 + e] + (jtile == 0 ? bo : 0.f);
        atomicAdd(&outp[(size_t)row * T + t], v);
      }
  }
}

extern "C" void kernel_launch(void* const* d_in, const int* in_sizes, int n_in,
                              void* d_out, int out_size, void* d_ws, size_t ws_size,
                              hipStream_t stream)
{
  const float* z    = (const float*)d_in[0];
  const float* Wzh  = (const float*)d_in[1];
  const float* bzh  = (const float*)d_in[2];
  const float* Wzc  = (const float*)d_in[3];
  const float* bzc  = (const float*)d_in[4];
  const float* Wih  = (const float*)d_in[5];
  const float* Whh  = (const float*)d_in[6];
  const float* b_ih = (const float*)d_in[7];
  const float* b_hh = (const float*)d_in[8];
  const float* Wout = (const float*)d_in[9];
  const float* bout = (const float*)d_in[10];
  const int*   tlen = (const int*)d_in[11];
  float* outp = (float*)d_out;

  char* ws = (char*)d_ws;
  size_t off = 0;
  auto alloc = [&](size_t bytes) -> char* {
    char* p = ws + off;
    off += (bytes + 255) & ~size_t(255);
    return p;
  };
  u16* wp_hi  = (u16*)alloc((size_t)G4H * Hn * 2);
  u16* wp_lo  = (u16*)alloc((size_t)G4H * Hn * 2);
  u16* hb_hi  = (u16*)alloc((size_t)2 * Bsz * Hn * 2);
  u16* hb_lo  = (u16*)alloc((size_t)2 * Bsz * Hn * 2);
  float* cbuf    = (float*)alloc((size_t)Bsz * Hn * 4);
  float* yinit   = (float*)alloc((size_t)Bsz * 4);
  float* bpack   = (float*)alloc((size_t)G4H * 4);
  float* wihpack = (float*)alloc((size_t)G4H * 4);

  repack_kernel<<<dim3(1024), dim3(256), 0, stream>>>(
      Whh, b_ih, b_hh, Wih, Wout, bout, wp_hi, wp_lo, bpack, wihpack);

  init_kernel<<<dim3(Bsz), dim3(256), 0, stream>>>(
      z, Wzh, bzh, Wzc, bzc, Wout, bout, hb_hi, hb_lo, cbuf, yinit);

  (void)hipMemsetAsync(outp, 0, (size_t)out_size * sizeof(float), stream);

  const int T_host = out_size / Bsz;   // output is (B, T, 1)
  for (int t = 0; t < T_host; ++t){
    step_kernel<<<dim3(NBLK), dim3(512), 0, stream>>>(
        wp_hi, wp_lo, bpack, wihpack, Wout, bout, yinit,
        hb_hi, hb_lo, cbuf, outp, tlen, t);
  }
}

// Round 9
// 9946.667 us; speedup vs baseline: 2.9149x; 1.0559x over previous
//
#include <hip/hip_runtime.h>

typedef unsigned short u16;
typedef unsigned int u32;
typedef __bf16 bf16x8 __attribute__((ext_vector_type(8)));
typedef float f32x4 __attribute__((ext_vector_type(4)));
typedef u16 u16x8 __attribute__((ext_vector_type(8)));

#define AS1 __attribute__((address_space(1)))
#define AS3 __attribute__((address_space(3)))

constexpr int Bsz = 512;   // batch
constexpr int LATn = 128;  // latent
constexpr int Hn  = 1024;  // hidden
constexpr int G4H = 4096;  // 4*H
constexpr int NBLK = 256;

__device__ __forceinline__ u16 f2bf(float x){
  u32 u = __float_as_uint(x);
  return (u16)((u + 0x7FFFu + ((u >> 16) & 1u)) >> 16);
}
__device__ __forceinline__ float bf2f(u16 h){ return __uint_as_float(((u32)h) << 16); }

__device__ __forceinline__ float sigm(float x){
  float e = __builtin_amdgcn_exp2f(x * -1.44269504088896f);
  return __builtin_amdgcn_rcpf(1.0f + e);
}
__device__ __forceinline__ float tanh_f(float x){
  float e = __builtin_amdgcn_exp2f(x * -2.88539008177793f);
  return __builtin_amdgcn_rcpf(1.0f + e) * 2.0f - 1.0f;
}

__device__ __forceinline__ bf16x8 ld8(const u16* p){
  u16x8 v = *reinterpret_cast<const u16x8*>(p);
  return __builtin_bit_cast(bf16x8, v);
}

__device__ __forceinline__ void load16_lds(const u16* g, u16* l){
  __builtin_amdgcn_global_load_lds((AS1 void*)(u16*)g, (AS3 void*)l, 16, 0, 0);
}

// ---------------- repack: fold y-feedback into weights, fp32 -> bf16 hi/lo ----------------
// W'[gc][k] = Whh[gc][k] + Wout[k]*Wih[gc];  bias' = b_ih + b_hh + bo*Wih
// packed col (within 8-j tile): drow = (jj>>3)*32 + g*8 + (jj&7)
__global__ void repack_kernel(
    const float* __restrict__ Whh, const float* __restrict__ b_ih, const float* __restrict__ b_hh,
    const float* __restrict__ Wih, const float* __restrict__ Wout, const float* __restrict__ bout,
    u16* wp_hi, u16* wp_lo, float* bpack, float* wihpack)
{
  const int idx0 = blockIdx.x * blockDim.x + threadIdx.x;
  const int stride = gridDim.x * blockDim.x;
  const float bo = bout[0];
  for (int i = idx0; i < G4H * Hn; i += stride){
    int row = i >> 10, k = i & 1023;
    int g = row >> 10, jj = row & 1023;
    int drow = (jj >> 3) * 32 + g * 8 + (jj & 7);
    float x = Whh[i] + Wout[k] * Wih[row];
    u16 hi = f2bf(x);
    wp_hi[drow * 1024 + k] = hi;
    wp_lo[drow * 1024 + k] = f2bf(x - bf2f(hi));
  }
  for (int i = idx0; i < G4H; i += stride){
    int g = i >> 10, jj = i & 1023;
    int drow = (jj >> 3) * 32 + g * 8 + (jj & 7);
    bpack[drow] = b_ih[i] + b_hh[i] + bo * Wih[i];
    wihpack[drow] = Wih[i];
  }
}

// ---------------- init: h0, c0, y_init (one block per batch row) ----------------
__global__ __launch_bounds__(256, 1) void init_kernel(
    const float* __restrict__ z,
    const float* __restrict__ Wzh, const float* __restrict__ bzh,
    const float* __restrict__ Wzc, const float* __restrict__ bzc,
    const float* __restrict__ Wout, const float* __restrict__ bout,
    u16* hb_hi, u16* hb_lo, float* cbuf, float* yinit)
{
  __shared__ float zrow[LATn];
  __shared__ float yred[256];
  const int b = blockIdx.x, tid = threadIdx.x;
  if (tid < LATn) zrow[tid] = z[b * LATn + tid];
  __syncthreads();
  float ysum = 0.f;
  #pragma unroll
  for (int jj = 0; jj < 4; ++jj){
    const int j = tid * 4 + jj;
    const float* wh = Wzh + (size_t)j * LATn;
    const float* wc = Wzc + (size_t)j * LATn;
    float sh = bzh[j], sc = bzc[j];
    for (int k = 0; k < LATn; ++k){
      const float zv = zrow[k];
      sh = fmaf(zv, wh[k], sh);
      sc = fmaf(zv, wc[k], sc);
    }
    const float h0 = tanh_f(sh);
    cbuf[(size_t)b * Hn + j] = tanh_f(sc);
    const u16 hi = f2bf(h0);
    hb_hi[(size_t)b * Hn + j] = hi;
    hb_lo[(size_t)b * Hn + j] = f2bf(h0 - bf2f(hi));
    ysum = fmaf(h0, Wout[j], ysum);
  }
  yred[tid] = ysum;
  __syncthreads();
  for (int s = 128; s > 0; s >>= 1){
    if (tid < s) yred[tid] += yred[tid + s];
    __syncthreads();
  }
  if (tid == 0) yinit[b] = yred[0] + bout[0];
}

// ---------------- per-step kernel (launched T times) ----------------
// 256 blocks x 512 threads, 1 block/CU (LDS-limited).
// rowg = (bid&7)>>2, jtile = (bid&3)*32 + (bid>>3); 8 waves x 32 rows; 8 j per block.
// W' hi+lo staged to LDS each step (L2/L3-resident); h double-buffered in global;
// c in global cbuf (disjoint RMW per block); y partials -> ypart (contention-free),
// reduced for step t-1 at the START of step t (kernel-boundary coherence).
__global__ __launch_bounds__(512, 1) void step_kernel(
    const u16* __restrict__ wp_hi, const u16* __restrict__ wp_lo,
    const float* __restrict__ bpack, const float* __restrict__ wihpack,
    const float* __restrict__ Wout, const float* __restrict__ bout,
    const float* __restrict__ yinit,
    u16* __restrict__ hb_hi, u16* __restrict__ hb_lo,
    float* __restrict__ cbuf, float* __restrict__ ypart,
    float* __restrict__ outp, const int* __restrict__ tlen, int t)
{
  __shared__ __align__(16) u16 ldsW[2 * 32768];  // 128 KiB: hi @0, lo @32768
  __shared__ float redbuf[8];

  const int T = tlen[0];
  if (t >= T) return;

  const int tid = threadIdx.x;
  const int lane = tid & 63, w = tid >> 6;
  const int r = lane & 15, q = lane >> 4;
  const int bid = blockIdx.x;
  const int rowg = (bid & 7) >> 2;
  const int jtile = (bid & 3) * 32 + (bid >> 3);
  const int j = jtile * 8 + (r & 7);
  const int row0 = rowg * 256 + w * 32;

  // ---- stage W' hi + lo into LDS (issue first; latency hidden under reduction) ----
  {
    const int a = tid >> 8;                 // 0 = hi, 1 = lo (wave-uniform)
    const int rem = tid & 255;
    const int col = rem >> 3, sp = rem & 7;
    const u16* wp = (a ? wp_lo : wp_hi) + (size_t)(jtile * 32 + col) * 1024 + (sp ^ (col & 7)) * 8;
    u16* dst = &ldsW[a * 32768 + (w & 3) * 512];   // wave-uniform base; HW adds lane*16B
    #pragma unroll 4
    for (int slab = 0; slab < 16; ++slab)
      load16_lds(wp + slab * 64, dst + slab * 2048);
  }

  const float bo = bout[0];
  const int r0red = rowg * 256 + jtile * 2;   // this block reduces rows r0red, r0red+1 of step t-1

  // ---- reduce previous step's y partials (overlaps with staging) ----
  if (t > 0 && tid < 256){
    const int pbp = (t - 1) & 1;
    const int rsel = tid >> 7, col = tid & 127;
    float v = ypart[pbp * 65536 + (r0red + rsel) * 128 + col];
    #pragma unroll
    for (int m = 1; m < 64; m <<= 1) v += __shfl_xor(v, m, 64);
    if (lane == 0) redbuf[tid >> 6] = v;
  }

  // per-lane constants
  float bias_r[2], wih_r[2];
  #pragma unroll
  for (int nt = 0; nt < 2; ++nt){
    bias_r[nt] = bpack[jtile * 32 + nt * 16 + r];
    wih_r[nt]  = wihpack[jtile * 32 + nt * 16 + r];
  }
  const float wout_r = Wout[j];

  const int pb = t & 1;
  const u16* hs_hi = hb_hi + pb * (Bsz * Hn);
  const u16* hs_lo = hb_lo + pb * (Bsz * Hn);
  u16* hd_hi = hb_hi + (pb ^ 1) * (Bsz * Hn);
  u16* hd_lo = hb_lo + (pb ^ 1) * (Bsz * Hn);

  // c state for this thread's (row, j) set
  float creg[8];
  #pragma unroll
  for (int mt = 0; mt < 2; ++mt)
    #pragma unroll
    for (int e = 0; e < 4; ++e)
      creg[mt * 4 + e] = cbuf[(size_t)(row0 + mt * 16 + q * 4 + e) * Hn + j];

  f32x4 acc[2][2];
  #pragma unroll
  for (int mt = 0; mt < 2; ++mt)
    #pragma unroll
    for (int nt = 0; nt < 2; ++nt)
      #pragma unroll
      for (int e = 0; e < 4; ++e)
        acc[mt][nt][e] = bias_r[nt];
  if (t == 0){
    // x0 = 0, not y_{-1}: subtract the folded y_init term once
    #pragma unroll
    for (int mt = 0; mt < 2; ++mt)
      #pragma unroll
      for (int e = 0; e < 4; ++e){
        const float yi = yinit[row0 + mt * 16 + q * 4 + e];
        #pragma unroll
        for (int nt = 0; nt < 2; ++nt)
          acc[mt][nt][e] -= yi * wih_r[nt];
      }
  }

  __syncthreads();   // staging + redbuf complete (barrier drains vmcnt)

  if (t > 0 && tid < 2)
    outp[(size_t)(r0red + tid) * T + (t - 1)] = redbuf[tid * 2] + redbuf[tid * 2 + 1] + bo;

  const u16* ha_hi = hs_hi + (size_t)(row0 + r) * Hn + q * 8;
  const u16* ha_lo = hs_lo + (size_t)(row0 + r) * Hn + q * 8;

  #pragma unroll 4
  for (int c = 0; c < 32; ++c){
    const int ko = c * 32;
    bf16x8 ahi[2], alo[2];
    #pragma unroll
    for (int mt = 0; mt < 2; ++mt){
      ahi[mt] = ld8(ha_hi + mt * 16 * Hn + ko);
      alo[mt] = ld8(ha_lo + mt * 16 * Hn + ko);
    }
    const int lo_ = (c >> 1) * 2048;
    const int slot = ((((c & 1) * 4 + q) ^ (r & 7))) * 8;
    bf16x8 bhi[2], blo[2];
    #pragma unroll
    for (int nt = 0; nt < 2; ++nt){
      bhi[nt] = ld8(&ldsW[lo_ + (nt * 16 + r) * 64 + slot]);
      blo[nt] = ld8(&ldsW[32768 + lo_ + (nt * 16 + r) * 64 + slot]);
    }
    #pragma unroll
    for (int mt = 0; mt < 2; ++mt)
      #pragma unroll
      for (int nt = 0; nt < 2; ++nt){
        acc[mt][nt] = __builtin_amdgcn_mfma_f32_16x16x32_bf16(ahi[mt], bhi[nt], acc[mt][nt], 0, 0, 0);
        acc[mt][nt] = __builtin_amdgcn_mfma_f32_16x16x32_bf16(ahi[mt], blo[nt], acc[mt][nt], 0, 0, 0);
        acc[mt][nt] = __builtin_amdgcn_mfma_f32_16x16x32_bf16(alo[mt], bhi[nt], acc[mt][nt], 0, 0, 0);
      }
  }

  // ---- pointwise LSTM cell (gates recombined via xor-8 shfl) ----
  float pp[8];
  #pragma unroll
  for (int mt = 0; mt < 2; ++mt)
    #pragma unroll
    for (int e = 0; e < 4; ++e){
      const int idx = mt * 4 + e;
      const float p0 = acc[mt][0][e], p1 = acc[mt][1][e];
      const float q0 = __shfl_xor(p0, 8, 64);
      const float q1 = __shfl_xor(p1, 8, 64);
      const bool hi8 = (r >> 3) != 0;
      const float vi = hi8 ? q0 : p0;
      const float vf = hi8 ? p0 : q0;
      const float vg = hi8 ? q1 : p1;
      const float vo = hi8 ? p1 : q1;
      const float gi = sigm(vi);
      const float gf = sigm(vf);
      const float gg = tanh_f(vg);
      const float go = sigm(vo);
      const float cn = gf * creg[idx] + gi * gg;
      creg[idx] = cn;
      const float hn = go * tanh_f(cn);
      const int row = row0 + mt * 16 + q * 4 + e;
      if (r < 8){
        const u16 hi = f2bf(hn);
        hd_hi[(size_t)row * Hn + j] = hi;
        hd_lo[(size_t)row * Hn + j] = f2bf(hn - bf2f(hi));
        cbuf[(size_t)row * Hn + j] = cn;
      }
      pp[idx] = hn * wout_r;
    }
  #pragma unroll
  for (int m = 1; m < 8; m <<= 1)
    #pragma unroll
    for (int idx = 0; idx < 8; ++idx)
      pp[idx] += __shfl_xor(pp[idx], m, 64);
  if (r == 0){
    #pragma unroll
    for (int mt = 0; mt < 2; ++mt)
      #pragma unroll
      for (int e = 0; e < 4; ++e){
        const int row = row0 + mt * 16 + q * 4 + e;
        ypart[pb * 65536 + (size_t)row * 128 + jtile] = pp[mt * 4 + e];
      }
  }
}

// ---------------- final reduce: outp[:, T-1] from the last step's partials ----------------
__global__ __launch_bounds__(128, 1) void final_reduce(
    const float* __restrict__ ypart, const float* __restrict__ bout,
    float* __restrict__ outp, const int* __restrict__ tlen)
{
  __shared__ float sm[2];
  const int T = tlen[0];
  const int pbp = (T - 1) & 1;
  const int row = blockIdx.x;
  const int tid = threadIdx.x;
  float v = ypart[pbp * 65536 + (size_t)row * 128 + tid];
  #pragma unroll
  for (int m = 1; m < 64; m <<= 1) v += __shfl_xor(v, m, 64);
  if ((tid & 63) == 0) sm[tid >> 6] = v;
  __syncthreads();
  if (tid == 0) outp[(size_t)row * T + (T - 1)] = sm[0] + sm[1] + bout[0];
}

extern "C" void kernel_launch(void* const* d_in, const int* in_sizes, int n_in,
                              void* d_out, int out_size, void* d_ws, size_t ws_size,
                              hipStream_t stream)
{
  const float* z    = (const float*)d_in[0];
  const float* Wzh  = (const float*)d_in[1];
  const float* bzh  = (const float*)d_in[2];
  const float* Wzc  = (const float*)d_in[3];
  const float* bzc  = (const float*)d_in[4];
  const float* Wih  = (const float*)d_in[5];
  const float* Whh  = (const float*)d_in[6];
  const float* b_ih = (const float*)d_in[7];
  const float* b_hh = (const float*)d_in[8];
  const float* Wout = (const float*)d_in[9];
  const float* bout = (const float*)d_in[10];
  const int*   tlen = (const int*)d_in[11];
  float* outp = (float*)d_out;

  char* ws = (char*)d_ws;
  size_t off = 0;
  auto alloc = [&](size_t bytes) -> char* {
    char* p = ws + off;
    off += (bytes + 255) & ~size_t(255);
    return p;
  };
  u16* wp_hi  = (u16*)alloc((size_t)G4H * Hn * 2);
  u16* wp_lo  = (u16*)alloc((size_t)G4H * Hn * 2);
  u16* hb_hi  = (u16*)alloc((size_t)2 * Bsz * Hn * 2);
  u16* hb_lo  = (u16*)alloc((size_t)2 * Bsz * Hn * 2);
  float* cbuf    = (float*)alloc((size_t)Bsz * Hn * 4);
  float* yinit   = (float*)alloc((size_t)Bsz * 4);
  float* bpack   = (float*)alloc((size_t)G4H * 4);
  float* wihpack = (float*)alloc((size_t)G4H * 4);
  float* ypart   = (float*)alloc((size_t)2 * Bsz * 128 * 4);

  repack_kernel<<<dim3(1024), dim3(256), 0, stream>>>(
      Whh, b_ih, b_hh, Wih, Wout, bout, wp_hi, wp_lo, bpack, wihpack);

  init_kernel<<<dim3(Bsz), dim3(256), 0, stream>>>(
      z, Wzh, bzh, Wzc, bzc, Wout, bout, hb_hi, hb_lo, cbuf, yinit);

  const int T_host = out_size / Bsz;   // output is (B, T, 1)
  for (int t = 0; t < T_host; ++t){
    step_kernel<<<dim3(NBLK), dim3(512), 0, stream>>>(
        wp_hi, wp_lo, bpack, wihpack, Wout, bout, yinit,
        hb_hi, hb_lo, cbuf, ypart, outp, tlen, t);
  }
  final_reduce<<<dim3(Bsz), dim3(128), 0, stream>>>(ypart, bout, outp, tlen);
}

// Round 10
// 9701.116 us; speedup vs baseline: 2.9887x; 1.0253x over previous
//
#include <hip/hip_runtime.h>

typedef unsigned short u16;
typedef unsigned int u32;
typedef __bf16 bf16x8 __attribute__((ext_vector_type(8)));
typedef float f32x4 __attribute__((ext_vector_type(4)));
typedef u16 u16x8 __attribute__((ext_vector_type(8)));

#define AS1 __attribute__((address_space(1)))
#define AS3 __attribute__((address_space(3)))

constexpr int Bsz = 512;   // batch
constexpr int LATn = 128;  // latent
constexpr int Hn  = 1024;  // hidden
constexpr int G4H = 4096;  // 4*H
constexpr int NBLK = 256;

__device__ __forceinline__ u16 f2bf(float x){
  u32 u = __float_as_uint(x);
  return (u16)((u + 0x7FFFu + ((u >> 16) & 1u)) >> 16);
}
__device__ __forceinline__ float bf2f(u16 h){ return __uint_as_float(((u32)h) << 16); }

__device__ __forceinline__ float sigm(float x){
  float e = __builtin_amdgcn_exp2f(x * -1.44269504088896f);
  return __builtin_amdgcn_rcpf(1.0f + e);
}
__device__ __forceinline__ float tanh_f(float x){
  float e = __builtin_amdgcn_exp2f(x * -2.88539008177793f);
  return __builtin_amdgcn_rcpf(1.0f + e) * 2.0f - 1.0f;
}

__device__ __forceinline__ bf16x8 ld8(const u16* p){
  u16x8 v = *reinterpret_cast<const u16x8*>(p);
  return __builtin_bit_cast(bf16x8, v);
}

__device__ __forceinline__ void load16_lds(const u16* g, u16* l){
  __builtin_amdgcn_global_load_lds((AS1 void*)(u16*)g, (AS3 void*)l, 16, 0, 0);
}

// ---------------- repack: fold y-feedback into weights, fp32 -> bf16 hi/lo ----------------
// W'[gc][k] = Whh[gc][k] + Wout[k]*Wih[gc];  bias' = b_ih + b_hh + bo*Wih
// packed col (within 8-j tile): drow = (jj>>3)*32 + g*8 + (jj&7)
__global__ void repack_kernel(
    const float* __restrict__ Whh, const float* __restrict__ b_ih, const float* __restrict__ b_hh,
    const float* __restrict__ Wih, const float* __restrict__ Wout, const float* __restrict__ bout,
    u16* wp_hi, u16* wp_lo, float* bpack, float* wihpack)
{
  const int idx0 = blockIdx.x * blockDim.x + threadIdx.x;
  const int stride = gridDim.x * blockDim.x;
  const float bo = bout[0];
  for (int i = idx0; i < G4H * Hn; i += stride){
    int row = i >> 10, k = i & 1023;
    int g = row >> 10, jj = row & 1023;
    int drow = (jj >> 3) * 32 + g * 8 + (jj & 7);
    float x = Whh[i] + Wout[k] * Wih[row];
    u16 hi = f2bf(x);
    wp_hi[drow * 1024 + k] = hi;
    wp_lo[drow * 1024 + k] = f2bf(x - bf2f(hi));
  }
  for (int i = idx0; i < G4H; i += stride){
    int g = i >> 10, jj = i & 1023;
    int drow = (jj >> 3) * 32 + g * 8 + (jj & 7);
    bpack[drow] = b_ih[i] + b_hh[i] + bo * Wih[i];
    wihpack[drow] = Wih[i];
  }
}

// ---------------- init: h0, c0, y_init (one block per batch row) ----------------
__global__ __launch_bounds__(256, 1) void init_kernel(
    const float* __restrict__ z,
    const float* __restrict__ Wzh, const float* __restrict__ bzh,
    const float* __restrict__ Wzc, const float* __restrict__ bzc,
    const float* __restrict__ Wout, const float* __restrict__ bout,
    u16* hb_hi, u16* hb_lo, float* cbuf, float* yinit)
{
  __shared__ float zrow[LATn];
  __shared__ float yred[256];
  const int b = blockIdx.x, tid = threadIdx.x;
  if (tid < LATn) zrow[tid] = z[b * LATn + tid];
  __syncthreads();
  float ysum = 0.f;
  #pragma unroll
  for (int jj = 0; jj < 4; ++jj){
    const int j = tid * 4 + jj;
    const float* wh = Wzh + (size_t)j * LATn;
    const float* wc = Wzc + (size_t)j * LATn;
    float sh = bzh[j], sc = bzc[j];
    for (int k = 0; k < LATn; ++k){
      const float zv = zrow[k];
      sh = fmaf(zv, wh[k], sh);
      sc = fmaf(zv, wc[k], sc);
    }
    const float h0 = tanh_f(sh);
    cbuf[(size_t)b * Hn + j] = tanh_f(sc);
    const u16 hi = f2bf(h0);
    hb_hi[(size_t)b * Hn + j] = hi;
    hb_lo[(size_t)b * Hn + j] = f2bf(h0 - bf2f(hi));
    ysum = fmaf(h0, Wout[j], ysum);
  }
  yred[tid] = ysum;
  __syncthreads();
  for (int s = 128; s > 0; s >>= 1){
    if (tid < s) yred[tid] += yred[tid + s];
    __syncthreads();
  }
  if (tid == 0) yinit[b] = yred[0] + bout[0];
}

// ---------------- per-step kernel (launched T times) ----------------
// 256 blocks x 512 threads, 1 block/CU (LDS-limited).
// rowg = (bid&7)>>2, jtile = (bid&3)*32 + (bid>>3); 8 waves x 32 rows; 8 j per block.
// W' hi+lo staged to LDS each step; A (h) read via depth-4 register prefetch ring,
// first 4 groups issued BEFORE the staging barrier so A-latency hides under the drain.
__global__ __launch_bounds__(512, 1) void step_kernel(
    const u16* __restrict__ wp_hi, const u16* __restrict__ wp_lo,
    const float* __restrict__ bpack, const float* __restrict__ wihpack,
    const float* __restrict__ Wout, const float* __restrict__ bout,
    const float* __restrict__ yinit,
    u16* __restrict__ hb_hi, u16* __restrict__ hb_lo,
    float* __restrict__ cbuf, float* __restrict__ ypart,
    float* __restrict__ outp, const int* __restrict__ tlen, int t)
{
  __shared__ __align__(16) u16 ldsW[2 * 32768];  // 128 KiB: hi @0, lo @32768
  __shared__ float redbuf[8];

  const int T = tlen[0];
  if (t >= T) return;

  const int tid = threadIdx.x;
  const int lane = tid & 63, w = tid >> 6;
  const int r = lane & 15, q = lane >> 4;
  const int bid = blockIdx.x;
  const int rowg = (bid & 7) >> 2;
  const int jtile = (bid & 3) * 32 + (bid >> 3);
  const int j = jtile * 8 + (r & 7);
  const int row0 = rowg * 256 + w * 32;

  // ---- stage W' hi + lo into LDS (issue first) ----
  {
    const int a = tid >> 8;                 // 0 = hi, 1 = lo (wave-uniform)
    const int rem = tid & 255;
    const int col = rem >> 3, sp = rem & 7;
    const u16* wp = (a ? wp_lo : wp_hi) + (size_t)(jtile * 32 + col) * 1024 + (sp ^ (col & 7)) * 8;
    u16* dst = &ldsW[a * 32768 + (w & 3) * 512];   // wave-uniform base; HW adds lane*16B
    #pragma unroll 4
    for (int slab = 0; slab < 16; ++slab)
      load16_lds(wp + slab * 64, dst + slab * 2048);
  }

  const float bo = bout[0];
  const int r0red = rowg * 256 + jtile * 2;   // this block reduces rows r0red, r0red+1 of step t-1

  // ---- reduce previous step's y partials (overlaps with staging) ----
  if (t > 0 && tid < 256){
    const int pbp = (t - 1) & 1;
    const int rsel = tid >> 7, col = tid & 127;
    float v = ypart[pbp * 65536 + (r0red + rsel) * 128 + col];
    #pragma unroll
    for (int m = 1; m < 64; m <<= 1) v += __shfl_xor(v, m, 64);
    if (lane == 0) redbuf[tid >> 6] = v;
  }

  // per-lane constants
  float bias_r[2], wih_r[2];
  #pragma unroll
  for (int nt = 0; nt < 2; ++nt){
    bias_r[nt] = bpack[jtile * 32 + nt * 16 + r];
    wih_r[nt]  = wihpack[jtile * 32 + nt * 16 + r];
  }
  const float wout_r = Wout[j];

  const int pb = t & 1;
  const u16* hs_hi = hb_hi + pb * (Bsz * Hn);
  const u16* hs_lo = hb_lo + pb * (Bsz * Hn);
  u16* hd_hi = hb_hi + (pb ^ 1) * (Bsz * Hn);
  u16* hd_lo = hb_lo + (pb ^ 1) * (Bsz * Hn);

  // c state for this thread's (row, j) set
  float creg[8];
  #pragma unroll
  for (int mt = 0; mt < 2; ++mt)
    #pragma unroll
    for (int e = 0; e < 4; ++e)
      creg[mt * 4 + e] = cbuf[(size_t)(row0 + mt * 16 + q * 4 + e) * Hn + j];

  f32x4 acc[2][2];
  #pragma unroll
  for (int mt = 0; mt < 2; ++mt)
    #pragma unroll
    for (int nt = 0; nt < 2; ++nt)
      #pragma unroll
      for (int e = 0; e < 4; ++e)
        acc[mt][nt][e] = bias_r[nt];
  if (t == 0){
    // x0 = 0, not y_{-1}: subtract the folded y_init term once
    #pragma unroll
    for (int mt = 0; mt < 2; ++mt)
      #pragma unroll
      for (int e = 0; e < 4; ++e){
        const float yi = yinit[row0 + mt * 16 + q * 4 + e];
        #pragma unroll
        for (int nt = 0; nt < 2; ++nt)
          acc[mt][nt][e] -= yi * wih_r[nt];
      }
  }

  const u16* ha_hi = hs_hi + (size_t)(row0 + r) * Hn + q * 8;
  const u16* ha_lo = hs_lo + (size_t)(row0 + r) * Hn + q * 8;

  // ---- depth-4 A prefetch ring; first 4 groups issued BEFORE the staging barrier ----
  bf16x8 rahi[4][2], ralo[4][2];
  #define ALOAD(cc, ss) {                              \
    const int ko_ = (cc) * 32;                         \
    rahi[ss][0] = ld8(ha_hi + ko_);                    \
    rahi[ss][1] = ld8(ha_hi + 16 * Hn + ko_);          \
    ralo[ss][0] = ld8(ha_lo + ko_);                    \
    ralo[ss][1] = ld8(ha_lo + 16 * Hn + ko_);          }

  ALOAD(0, 0); ALOAD(1, 1); ALOAD(2, 2); ALOAD(3, 3);

  __syncthreads();   // staging + redbuf + first A-groups complete

  if (t > 0 && tid < 2)
    outp[(size_t)(r0red + tid) * T + (t - 1)] = redbuf[tid * 2] + redbuf[tid * 2 + 1] + bo;

  #pragma unroll 4
  for (int c = 0; c < 32; ++c){
    const int slot = c & 3;
    const int lo_ = (c >> 1) * 2048;
    const int sslot = ((((c & 1) * 4 + q) ^ (r & 7))) * 8;
    bf16x8 bhi[2], blo[2];
    #pragma unroll
    for (int nt = 0; nt < 2; ++nt){
      bhi[nt] = ld8(&ldsW[lo_ + (nt * 16 + r) * 64 + sslot]);
      blo[nt] = ld8(&ldsW[32768 + lo_ + (nt * 16 + r) * 64 + sslot]);
    }
    bf16x8 cahi[2], calo[2];
    #pragma unroll
    for (int mt = 0; mt < 2; ++mt){
      cahi[mt] = rahi[slot][mt];
      calo[mt] = ralo[slot][mt];
    }
    if (c < 28) ALOAD(c + 4, slot);
    #pragma unroll
    for (int mt = 0; mt < 2; ++mt)
      #pragma unroll
      for (int nt = 0; nt < 2; ++nt){
        acc[mt][nt] = __builtin_amdgcn_mfma_f32_16x16x32_bf16(cahi[mt], bhi[nt], acc[mt][nt], 0, 0, 0);
        acc[mt][nt] = __builtin_amdgcn_mfma_f32_16x16x32_bf16(cahi[mt], blo[nt], acc[mt][nt], 0, 0, 0);
        acc[mt][nt] = __builtin_amdgcn_mfma_f32_16x16x32_bf16(calo[mt], bhi[nt], acc[mt][nt], 0, 0, 0);
      }
  }
  #undef ALOAD

  // ---- pointwise LSTM cell (gates recombined via xor-8 shfl) ----
  float pp[8];
  #pragma unroll
  for (int mt = 0; mt < 2; ++mt)
    #pragma unroll
    for (int e = 0; e < 4; ++e){
      const int idx = mt * 4 + e;
      const float p0 = acc[mt][0][e], p1 = acc[mt][1][e];
      const float q0 = __shfl_xor(p0, 8, 64);
      const float q1 = __shfl_xor(p1, 8, 64);
      const bool hi8 = (r >> 3) != 0;
      const float vi = hi8 ? q0 : p0;
      const float vf = hi8 ? p0 : q0;
      const float vg = hi8 ? q1 : p1;
      const float vo = hi8 ? p1 : q1;
      const float gi = sigm(vi);
      const float gf = sigm(vf);
      const float gg = tanh_f(vg);
      const float go = sigm(vo);
      const float cn = gf * creg[idx] + gi * gg;
      creg[idx] = cn;
      const float hn = go * tanh_f(cn);
      const int row = row0 + mt * 16 + q * 4 + e;
      if (r < 8){
        const u16 hi = f2bf(hn);
        hd_hi[(size_t)row * Hn + j] = hi;
        hd_lo[(size_t)row * Hn + j] = f2bf(hn - bf2f(hi));
        cbuf[(size_t)row * Hn + j] = cn;
      }
      pp[idx] = hn * wout_r;
    }
  #pragma unroll
  for (int m = 1; m < 8; m <<= 1)
    #pragma unroll
    for (int idx = 0; idx < 8; ++idx)
      pp[idx] += __shfl_xor(pp[idx], m, 64);
  if (r == 0){
    #pragma unroll
    for (int mt = 0; mt < 2; ++mt)
      #pragma unroll
      for (int e = 0; e < 4; ++e){
        const int row = row0 + mt * 16 + q * 4 + e;
        ypart[pb * 65536 + (size_t)row * 128 + jtile] = pp[mt * 4 + e];
      }
  }
}

// ---------------- final reduce: outp[:, T-1] from the last step's partials ----------------
__global__ __launch_bounds__(128, 1) void final_reduce(
    const float* __restrict__ ypart, const float* __restrict__ bout,
    float* __restrict__ outp, const int* __restrict__ tlen)
{
  __shared__ float sm[2];
  const int T = tlen[0];
  const int pbp = (T - 1) & 1;
  const int row = blockIdx.x;
  const int tid = threadIdx.x;
  float v = ypart[pbp * 65536 + (size_t)row * 128 + tid];
  #pragma unroll
  for (int m = 1; m < 64; m <<= 1) v += __shfl_xor(v, m, 64);
  if ((tid & 63) == 0) sm[tid >> 6] = v;
  __syncthreads();
  if (tid == 0) outp[(size_t)row * T + (T - 1)] = sm[0] + sm[1] + bout[0];
}

extern "C" void kernel_launch(void* const* d_in, const int* in_sizes, int n_in,
                              void* d_out, int out_size, void* d_ws, size_t ws_size,
                              hipStream_t stream)
{
  const float* z    = (const float*)d_in[0];
  const float* Wzh  = (const float*)d_in[1];
  const float* bzh  = (const float*)d_in[2];
  const float* Wzc  = (const float*)d_in[3];
  const float* bzc  = (const float*)d_in[4];
  const float* Wih  = (const float*)d_in[5];
  const float* Whh  = (const float*)d_in[6];
  const float* b_ih = (const float*)d_in[7];
  const float* b_hh = (const float*)d_in[8];
  const float* Wout = (const float*)d_in[9];
  const float* bout = (const float*)d_in[10];
  const int*   tlen = (const int*)d_in[11];
  float* outp = (float*)d_out;

  char* ws = (char*)d_ws;
  size_t off = 0;
  auto alloc = [&](size_t bytes) -> char* {
    char* p = ws + off;
    off += (bytes + 255) & ~size_t(255);
    return p;
  };
  u16* wp_hi  = (u16*)alloc((size_t)G4H * Hn * 2);
  u16* wp_lo  = (u16*)alloc((size_t)G4H * Hn * 2);
  u16* hb_hi  = (u16*)alloc((size_t)2 * Bsz * Hn * 2);
  u16* hb_lo  = (u16*)alloc((size_t)2 * Bsz * Hn * 2);
  float* cbuf    = (float*)alloc((size_t)Bsz * Hn * 4);
  float* yinit   = (float*)alloc((size_t)Bsz * 4);
  float* bpack   = (float*)alloc((size_t)G4H * 4);
  float* wihpack = (float*)alloc((size_t)G4H * 4);
  float* ypart   = (float*)alloc((size_t)2 * Bsz * 128 * 4);

  repack_kernel<<<dim3(1024), dim3(256), 0, stream>>>(
      Whh, b_ih, b_hh, Wih, Wout, bout, wp_hi, wp_lo, bpack, wihpack);

  init_kernel<<<dim3(Bsz), dim3(256), 0, stream>>>(
      z, Wzh, bzh, Wzc, bzc, Wout, bout, hb_hi, hb_lo, cbuf, yinit);

  const int T_host = out_size / Bsz;   // output is (B, T, 1)
  for (int t = 0; t < T_host; ++t){
    step_kernel<<<dim3(NBLK), dim3(512), 0, stream>>>(
        wp_hi, wp_lo, bpack, wihpack, Wout, bout, yinit,
        hb_hi, hb_lo, cbuf, ypart, outp, tlen, t);
  }
  final_reduce<<<dim3(Bsz), dim3(128), 0, stream>>>(ypart, bout, outp, tlen);
}